// Round 6
// baseline (56.735 us; speedup 1.0000x reference)
//
#include <hip/hip_runtime.h>
#include <math.h>

constexpr int N_ = 8, C_ = 256, H_ = 128, W_ = 128, G_ = 32;
constexpr int HW  = H_ * W_;        // 16384
constexpr int CHW = C_ * HW;        // 4194304

typedef float f4 __attribute__((ext_vector_type(4)));

// Barrier-free, LDS-free fused kernel.
// One WAVE owns a 16-pixel tile x all 256 channels:
//   lane = 4*chunk + q : chunk (0..15) -> 16 channels, q (0..3) -> pixel f4.
// Each thread: 16 f4 loads (64 VGPRs), mask computed in the load shadow,
// channel sum closed by shfl_xor(4/8/16/32) -- fully in-wave, no sync.
// Waves desync naturally -> read & write HBM streams overlap continuously.
__global__ __launch_bounds__(256, 4) void fused_exc_kernel(
    const float* __restrict__ x, const float* __restrict__ bb,
    const int* __restrict__ stride_p, const int* __restrict__ epoch_p,
    float* __restrict__ out)
{
    int tid   = blockIdx.x * 256 + threadIdx.x;
    int lane  = tid & 63;
    int gw    = tid >> 6;         // global wave id, 0..8191
    int chunk = lane >> 2;        // 16-channel group 0..15
    int q     = lane & 3;         // f4 column within the 16-pixel tile

    int pix0 = gw << 4;           // tile base pixel (16 px, row-aligned)
    int n    = pix0 >> 14;        // / HW
    int hw   = pix0 & (HW - 1);

    size_t goff = (size_t)n * CHW + (size_t)(chunk * 16) * HW + (size_t)hw + q * 4;
    const float* xp = x + goff;

    f4 v[16];
    #pragma unroll
    for (int k = 0; k < 16; ++k)
        v[k] = *reinterpret_cast<const f4*>(xp + (size_t)k * HW);

    // --- independent of x: schedule scalars + per-pixel mask (4 pixels) ---
    float inv   = 1.0f / (float)(*stride_p);
    float alpha = 0.5f * (1.0f + cosf((float)M_PI * (float)(*epoch_p) / 22.0f));
    float scale = alpha / (float)C_;

    float hf = (float)(hw >> 7);
    float w0 = (float)((hw & 127) + q * 4);
    const f4* bbp = reinterpret_cast<const f4*>(bb) + n * G_;   // wave-uniform
    int m = 0;
    #pragma unroll 4
    for (int g = 0; g < G_; ++g) {
        f4 bv = bbp[g];
        float x1 = floorf(bv.x * inv), y1 = floorf(bv.y * inv);
        float x2 = ceilf (bv.z * inv), y2 = ceilf (bv.w * inv);
        if (hf >= y1 && hf < y2) {
            #pragma unroll
            for (int j = 0; j < 4; ++j) {
                float wf = w0 + (float)j;
                if (wf >= x1 && wf < x2) m |= 1 << j;
            }
        }
    }

    // --- channel reduction: 16 locals + 4-step in-wave tree over chunks ---
    f4 s = v[0];
    #pragma unroll
    for (int k = 1; k < 16; ++k) s += v[k];

    #pragma unroll
    for (int off = 4; off <= 32; off <<= 1) {
        s.x += __shfl_xor(s.x, off);
        s.y += __shfl_xor(s.y, off);
        s.z += __shfl_xor(s.z, off);
        s.w += __shfl_xor(s.w, off);
    }

    f4 e4;
    e4.x = (m & 1) ? s.x * scale : 0.f;
    e4.y = (m & 2) ? s.y * scale : 0.f;
    e4.z = (m & 4) ? s.z * scale : 0.f;
    e4.w = (m & 8) ? s.w * scale : 0.f;

    float* op = out + goff;
    #pragma unroll
    for (int k = 0; k < 16; ++k) {
        f4 o = v[k] + e4;
        __builtin_nontemporal_store(o, reinterpret_cast<f4*>(op + (size_t)k * HW));
    }
}

extern "C" void kernel_launch(void* const* d_in, const int* in_sizes, int n_in,
                              void* d_out, int out_size, void* d_ws, size_t ws_size,
                              hipStream_t stream) {
    const float* x  = (const float*)d_in[0];
    const float* bb = (const float*)d_in[1];
    const int* stride_p = (const int*)d_in[2];
    const int* epoch_p  = (const int*)d_in[3];
    float* out = (float*)d_out;

    // 8192 waves (one per 16-pixel tile) = 524288 threads = 2048 blocks
    int grid = (N_ * HW / 16) / 4;   // 2048 blocks of 4 waves
    fused_exc_kernel<<<grid, 256, 0, stream>>>(x, bb, stride_p, epoch_p, out);
}

// Round 7
// 47.068 us; speedup vs baseline: 1.2054x; 1.2054x over previous
//
#include <hip/hip_runtime.h>
#include <math.h>

constexpr int N_ = 8, C_ = 256, H_ = 128, W_ = 128, G_ = 32;
constexpr int HW  = H_ * W_;        // 16384
constexpr int CHW = C_ * HW;        // 4194304

typedef float f4 __attribute__((ext_vector_type(4)));

// Two-tile software-pipelined fused kernel (R5 structure, doubled depth).
// Block = one row (128 px) x 256 ch = two 64-px tiles A|B.
// 512 threads: c0 = tid>>4 (32 channel groups of 8), q = tid&15 (pixel f4).
// Issue all 16 loads -> mask A+B in load shadow -> reduce A, reduce B ->
// ONE barrier -> broadcast+store A, broadcast+store B. Registers pinned
// post-reduce so the compiler can't demote the tile to a re-load.
__global__ __launch_bounds__(512, 2) void fused_exc_kernel(
    const float* __restrict__ x, const float* __restrict__ bb,
    const int* __restrict__ stride_p, const int* __restrict__ epoch_p,
    float* __restrict__ out)
{
    __shared__ f4 psum[2][8][16];     // 4 KiB wave partials (A,B)

    int bid = blockIdx.x;             // 1024 blocks, one per (n,row)
    int n   = bid >> 7;               // 8 n
    int row = bid & 127;              // 128 rows

    int tid  = threadIdx.x;
    int wv   = tid >> 6;              // wave 0..7
    int lane = tid & 63;
    int c0   = tid >> 4;              // channel group 0..31
    int q    = tid & 15;              // f4 index within a 64-px half-row

    size_t gA = (size_t)n * CHW + (size_t)c0 * HW + (size_t)row * W_ + q * 4;
    size_t gB = gA + 64;              // second half of the row
    const float* xpA = x + gA;
    const float* xpB = x + gB;

    // Issue ALL loads first (16 in flight/thread); everything until the
    // sums is independent of them.
    f4 vA[8], vB[8];
    #pragma unroll
    for (int k = 0; k < 8; ++k)
        vA[k] = *reinterpret_cast<const f4*>(xpA + (size_t)(32 * k) * HW);
    #pragma unroll
    for (int k = 0; k < 8; ++k)
        vB[k] = *reinterpret_cast<const f4*>(xpB + (size_t)(32 * k) * HW);

    // --- independent of x: schedule scalars + masks for both halves ---
    float inv   = 1.0f / (float)(*stride_p);
    float alpha = 0.5f * (1.0f + cosf((float)M_PI * (float)(*epoch_p) / 22.0f));
    float scale = alpha / (float)C_;

    float hf  = (float)row;
    float w0A = (float)(q * 4);
    float w0B = w0A + 64.0f;
    const f4* bbp = reinterpret_cast<const f4*>(bb) + n * G_;   // wave-uniform
    int mA = 0, mB = 0;
    #pragma unroll 4
    for (int g = 0; g < G_; ++g) {
        f4 bv = bbp[g];               // uniform index -> scalar loads
        float x1 = floorf(bv.x * inv), y1 = floorf(bv.y * inv);
        float x2 = ceilf (bv.z * inv), y2 = ceilf (bv.w * inv);
        if (hf >= y1 && hf < y2) {
            #pragma unroll
            for (int j = 0; j < 4; ++j) {
                float wfA = w0A + (float)j;
                float wfB = w0B + (float)j;
                if (wfA >= x1 && wfA < x2) mA |= 1 << j;
                if (wfB >= x1 && wfB < x2) mB |= 1 << j;
            }
        }
    }

    // --- reduce A ---
    f4 sA = vA[0];
    #pragma unroll
    for (int k = 1; k < 8; ++k) sA += vA[k];
    sA.x += __shfl_xor(sA.x, 16); sA.y += __shfl_xor(sA.y, 16);
    sA.z += __shfl_xor(sA.z, 16); sA.w += __shfl_xor(sA.w, 16);
    sA.x += __shfl_xor(sA.x, 32); sA.y += __shfl_xor(sA.y, 32);
    sA.z += __shfl_xor(sA.z, 32); sA.w += __shfl_xor(sA.w, 32);
    if (lane < 16) psum[0][wv][q] = sA;

    // --- reduce B ---
    f4 sB = vB[0];
    #pragma unroll
    for (int k = 1; k < 8; ++k) sB += vB[k];
    sB.x += __shfl_xor(sB.x, 16); sB.y += __shfl_xor(sB.y, 16);
    sB.z += __shfl_xor(sB.z, 16); sB.w += __shfl_xor(sB.w, 16);
    sB.x += __shfl_xor(sB.x, 32); sB.y += __shfl_xor(sB.y, 32);
    sB.z += __shfl_xor(sB.z, 32); sB.w += __shfl_xor(sB.w, 32);
    if (lane < 16) psum[1][wv][q] = sB;

    // Pin the tiles in registers (loads already waited for the sums, so
    // this costs nothing but blocks the spill-to-reload transform).
    #pragma unroll
    for (int k = 0; k < 8; ++k) {
        asm volatile("" : "+v"(vA[k]));
        asm volatile("" : "+v"(vB[k]));
    }

    __syncthreads();

    // --- finish + store A ---
    f4 sumA = psum[0][0][q];
    #pragma unroll
    for (int w = 1; w < 8; ++w) sumA += psum[0][w][q];
    f4 eA;
    eA.x = (mA & 1) ? sumA.x * scale : 0.f;
    eA.y = (mA & 2) ? sumA.y * scale : 0.f;
    eA.z = (mA & 4) ? sumA.z * scale : 0.f;
    eA.w = (mA & 8) ? sumA.w * scale : 0.f;
    float* opA = out + gA;
    #pragma unroll
    for (int k = 0; k < 8; ++k) {
        f4 o = vA[k] + eA;
        __builtin_nontemporal_store(o, reinterpret_cast<f4*>(opA + (size_t)(32 * k) * HW));
    }

    // --- finish + store B ---
    f4 sumB = psum[1][0][q];
    #pragma unroll
    for (int w = 1; w < 8; ++w) sumB += psum[1][w][q];
    f4 eB;
    eB.x = (mB & 1) ? sumB.x * scale : 0.f;
    eB.y = (mB & 2) ? sumB.y * scale : 0.f;
    eB.z = (mB & 4) ? sumB.z * scale : 0.f;
    eB.w = (mB & 8) ? sumB.w * scale : 0.f;
    float* opB = out + gB;
    #pragma unroll
    for (int k = 0; k < 8; ++k) {
        f4 o = vB[k] + eB;
        __builtin_nontemporal_store(o, reinterpret_cast<f4*>(opB + (size_t)(32 * k) * HW));
    }
}

extern "C" void kernel_launch(void* const* d_in, const int* in_sizes, int n_in,
                              void* d_out, int out_size, void* d_ws, size_t ws_size,
                              hipStream_t stream) {
    const float* x  = (const float*)d_in[0];
    const float* bb = (const float*)d_in[1];
    const int* stride_p = (const int*)d_in[2];
    const int* epoch_p  = (const int*)d_in[3];
    float* out = (float*)d_out;

    int grid = N_ * H_;   // 1024 blocks, one per row
    fused_exc_kernel<<<grid, 512, 0, stream>>>(x, bb, stride_p, epoch_p, out);
}